// Round 7
// baseline (491.132 us; speedup 1.0000x reference)
//
#include <hip/hip_runtime.h>
#include <math.h>

#define B_ 2
#define S_ 2048
#define D_ 1024
#define H_ 16
#define HD 64
#define M_ (B_ * S_)     // 4096
#define N_QKV (3 * D_)   // 3072

typedef short short8 __attribute__((ext_vector_type(8)));
typedef float floatx4 __attribute__((ext_vector_type(4)));

static __device__ __forceinline__ unsigned short f2bf_rne(float x) {
    union { float f; unsigned u; } v; v.f = x;
    unsigned r = v.u + 0x7FFFu + ((v.u >> 16) & 1u);
    return (unsigned short)(r >> 16);
}
static __device__ __forceinline__ float bf2f(unsigned short b) {
    union { unsigned u; float f; } v; v.u = ((unsigned)b) << 16;
    return v.f;
}
// RNE split: x = hi + lo + eps, |eps| ~ 2^-17 |x|
static __device__ __forceinline__ void split2(float x, unsigned short& h, unsigned short& l) {
    h = f2bf_rne(x);
    l = f2bf_rne(x - bf2f(h));
}

// ---------------------------------------------------------------------------
// prep_wT: W[K=1024][N] fp32 -> WT hi/lo bf16 [N][1024]. 64x64 LDS transpose.
// Runs once per launch (~4 us each); removes all B-conversion from GEMM loops.
// ---------------------------------------------------------------------------
__global__ __launch_bounds__(256) void prep_wT(
    const float* __restrict__ W, int N,
    unsigned short* __restrict__ Thi, unsigned short* __restrict__ Tlo)
{
    __shared__ float Ws[64][68];
    const int t  = threadIdx.x;
    const int n0 = blockIdx.x * 64, k0 = blockIdx.y * 64;
    {
        const int kl = t >> 4, nl = (t & 15) * 4;
        const float* src = W + (size_t)(k0 + kl) * N + n0 + nl;
#pragma unroll
        for (int g = 0; g < 4; g++)
            *(float4*)&Ws[kl + g * 16][nl] = *(const float4*)(src + (size_t)g * 16 * N);
    }
    __syncthreads();
    {
        const int nl = t >> 2, ks = (t & 3) * 16;
        short8 h0, h1, l0, l1;
#pragma unroll
        for (int j = 0; j < 8; j++) {
            unsigned short hh, ll;
            split2(Ws[ks + j][nl], hh, ll);
            h0[j] = (short)hh; l0[j] = (short)ll;
        }
#pragma unroll
        for (int j = 0; j < 8; j++) {
            unsigned short hh, ll;
            split2(Ws[ks + 8 + j][nl], hh, ll);
            h1[j] = (short)hh; l1[j] = (short)ll;
        }
        unsigned short* dh = Thi + (size_t)(n0 + nl) * D_ + k0 + ks;
        unsigned short* dl = Tlo + (size_t)(n0 + nl) * D_ + k0 + ks;
        *(short8*)dh = h0; *(short8*)(dh + 8) = h1;
        *(short8*)dl = l0; *(short8*)(dl + 8) = l1;
    }
}

// ---------------------------------------------------------------------------
// QKV GEMM: hs @ W + b, split-bf16 3-MFMA. B side pre-split (pure copy
// staging); A side converted in-loop (not k-redundant). LDS row stride 40 u16
// (20 banks) -> 2-way max conflicts on all frag reads/writes. Register
// prefetch of next k-tile hidden behind MFMA. Epilogue writes pre-split
// Q*(1/8), K [s][d] and V^T [b][h][d][s].
// ---------------------------------------------------------------------------
#define AST 40   // u16 LDS row stride

__global__ __launch_bounds__(256) void gemm_qkv(
    const float* __restrict__ A,
    const unsigned short* __restrict__ BThi, const unsigned short* __restrict__ BTlo,
    const float* __restrict__ bias,
    unsigned short* __restrict__ Qhi, unsigned short* __restrict__ Qlo,
    unsigned short* __restrict__ Khi, unsigned short* __restrict__ Klo,
    unsigned short* __restrict__ vThi, unsigned short* __restrict__ vTlo)
{
    __shared__ unsigned short sAh[128 * AST], sAl[128 * AST];
    __shared__ unsigned short sBh[128 * AST], sBl[128 * AST];

    const int t    = threadIdx.x;
    const int m0   = blockIdx.y * 128, n0 = blockIdx.x * 128;
    const int lane = t & 63, wave = t >> 6;
    const int lm   = lane & 15, quad = lane >> 4;
    const int wm   = (wave >> 1) * 64, wn = (wave & 1) * 64;

    const int srow = t >> 1, sseg = (t & 1) * 16;

    const float* Ap = A + (size_t)(m0 + srow) * D_ + sseg;
    const unsigned short* Bph = BThi + (size_t)(n0 + srow) * D_ + sseg;
    const unsigned short* Bpl = BTlo + (size_t)(n0 + srow) * D_ + sseg;

    floatx4 acc[4][4];
#pragma unroll
    for (int i = 0; i < 4; i++)
#pragma unroll
        for (int j = 0; j < 4; j++)
#pragma unroll
            for (int r = 0; r < 4; r++) acc[i][j][r] = 0.f;

    float4 af[4];
    uint4 pbh[2], pbl[2];
    af[0] = *(const float4*)(Ap);     af[1] = *(const float4*)(Ap + 4);
    af[2] = *(const float4*)(Ap + 8); af[3] = *(const float4*)(Ap + 12);
    pbh[0] = *(const uint4*)(Bph);    pbh[1] = *(const uint4*)(Bph + 8);
    pbl[0] = *(const uint4*)(Bpl);    pbl[1] = *(const uint4*)(Bpl + 8);

    for (int k0 = 0; k0 < D_; k0 += 32) {
        // convert prefetched A (registers only)
        short8 ah0, ah1, al0, al1;
#pragma unroll
        for (int g = 0; g < 4; g++) {
            float xs[4] = {af[g].x, af[g].y, af[g].z, af[g].w};
#pragma unroll
            for (int e = 0; e < 4; e++) {
                unsigned short hh, ll;
                split2(xs[e], hh, ll);
                if (g < 2) { ah0[g * 4 + e] = (short)hh; al0[g * 4 + e] = (short)ll; }
                else       { ah1[(g - 2) * 4 + e] = (short)hh; al1[(g - 2) * 4 + e] = (short)ll; }
            }
        }
        __syncthreads();   // consumers of previous tile done
        {
            unsigned short* a = &sAh[srow * AST + sseg];
            unsigned short* b = &sAl[srow * AST + sseg];
            unsigned short* c = &sBh[srow * AST + sseg];
            unsigned short* d = &sBl[srow * AST + sseg];
            *(short8*)a = ah0; *(short8*)(a + 8) = ah1;
            *(short8*)b = al0; *(short8*)(b + 8) = al1;
            *(uint4*)c = pbh[0]; *(uint4*)(c + 8) = pbh[1];
            *(uint4*)d = pbl[0]; *(uint4*)(d + 8) = pbl[1];
        }
        __syncthreads();   // tile staged

        if (k0 + 32 < D_) {   // prefetch next tile (latency hidden by MFMAs)
            const float* an = Ap + k0 + 32;
            af[0] = *(const float4*)(an);     af[1] = *(const float4*)(an + 4);
            af[2] = *(const float4*)(an + 8); af[3] = *(const float4*)(an + 12);
            const unsigned short* bh = Bph + k0 + 32;
            const unsigned short* bl = Bpl + k0 + 32;
            pbh[0] = *(const uint4*)(bh); pbh[1] = *(const uint4*)(bh + 8);
            pbl[0] = *(const uint4*)(bl); pbl[1] = *(const uint4*)(bl + 8);
        }

        short8 bhf[4], blf[4];
#pragma unroll
        for (int nb = 0; nb < 4; nb++) {
            const int r = wn + nb * 16 + lm;
            bhf[nb] = *(const short8*)&sBh[r * AST + quad * 8];
            blf[nb] = *(const short8*)&sBl[r * AST + quad * 8];
        }
#pragma unroll
        for (int mb = 0; mb < 4; mb++) {
            const int r = wm + mb * 16 + lm;
            short8 ah = *(const short8*)&sAh[r * AST + quad * 8];
            short8 al = *(const short8*)&sAl[r * AST + quad * 8];
#pragma unroll
            for (int nb = 0; nb < 4; nb++) {
                acc[mb][nb] = __builtin_amdgcn_mfma_f32_16x16x32_bf16(ah, bhf[nb], acc[mb][nb], 0, 0, 0);
                acc[mb][nb] = __builtin_amdgcn_mfma_f32_16x16x32_bf16(al, bhf[nb], acc[mb][nb], 0, 0, 0);
                acc[mb][nb] = __builtin_amdgcn_mfma_f32_16x16x32_bf16(ah, blf[nb], acc[mb][nb], 0, 0, 0);
            }
        }
    }

    const int nmode = n0 >> 10;   // 0=Q, 1=K, 2=V (block-uniform)
    if (nmode == 0) {
#pragma unroll
        for (int nb = 0; nb < 4; nb++) {
            const int c = n0 + wn + nb * 16 + lm;
            const float bv = bias[c];
#pragma unroll
            for (int mb = 0; mb < 4; mb++) {
                const int rowb = m0 + wm + mb * 16 + quad * 4;
#pragma unroll
                for (int r = 0; r < 4; r++) {
                    unsigned short hh, ll;
                    split2((acc[mb][nb][r] + bv) * 0.125f, hh, ll);
                    Qhi[(size_t)(rowb + r) * D_ + c] = hh;
                    Qlo[(size_t)(rowb + r) * D_ + c] = ll;
                }
            }
        }
    } else if (nmode == 1) {
#pragma unroll
        for (int nb = 0; nb < 4; nb++) {
            const int c = n0 + wn + nb * 16 + lm;
            const float bv = bias[c];
            const int cq = c - 1024;
#pragma unroll
            for (int mb = 0; mb < 4; mb++) {
                const int rowb = m0 + wm + mb * 16 + quad * 4;
#pragma unroll
                for (int r = 0; r < 4; r++) {
                    unsigned short hh, ll;
                    split2(acc[mb][nb][r] + bv, hh, ll);
                    Khi[(size_t)(rowb + r) * D_ + cq] = hh;
                    Klo[(size_t)(rowb + r) * D_ + cq] = ll;
                }
            }
        }
    } else {
#pragma unroll
        for (int nb = 0; nb < 4; nb++) {
            const int c = n0 + wn + nb * 16 + lm;
            const float bv = bias[c];
            const int cq = c - 2048;
            const int hh_ = cq >> 6, dd = cq & 63;
#pragma unroll
            for (int mb = 0; mb < 4; mb++) {
                const int rowb = m0 + wm + mb * 16 + quad * 4;
                const int bb = rowb >> 11, ss = rowb & 2047;
                unsigned short hv[4], lv[4];
#pragma unroll
                for (int r = 0; r < 4; r++)
                    split2(acc[mb][nb][r] + bv, hv[r], lv[r]);
                const size_t idx = ((size_t)((bb * 16 + hh_) * 64 + dd)) * S_ + ss;
                *(uint2*)&vThi[idx] = make_uint2((unsigned)hv[0] | ((unsigned)hv[1] << 16),
                                                 (unsigned)hv[2] | ((unsigned)hv[3] << 16));
                *(uint2*)&vTlo[idx] = make_uint2((unsigned)lv[0] | ((unsigned)lv[1] << 16),
                                                 (unsigned)lv[2] | ((unsigned)lv[3] << 16));
            }
        }
    }
}

// ---------------------------------------------------------------------------
// Proj GEMM: attn(pre-split by flash) @ projW^T(pre-split) + bias -> fp32.
// Pure-copy staging both sides; zero conversions in the K-loop.
// ---------------------------------------------------------------------------
__global__ __launch_bounds__(256) void gemm_out(
    const unsigned short* __restrict__ Ahi, const unsigned short* __restrict__ Alo,
    const unsigned short* __restrict__ BThi, const unsigned short* __restrict__ BTlo,
    const float* __restrict__ bias, float* __restrict__ C)
{
    __shared__ unsigned short sAh[128 * AST], sAl[128 * AST];
    __shared__ unsigned short sBh[128 * AST], sBl[128 * AST];

    const int t    = threadIdx.x;
    const int m0   = blockIdx.y * 128, n0 = blockIdx.x * 128;
    const int lane = t & 63, wave = t >> 6;
    const int lm   = lane & 15, quad = lane >> 4;
    const int wm   = (wave >> 1) * 64, wn = (wave & 1) * 64;

    const int srow = t >> 1, sseg = (t & 1) * 16;

    const unsigned short* Aph = Ahi + (size_t)(m0 + srow) * D_ + sseg;
    const unsigned short* Apl = Alo + (size_t)(m0 + srow) * D_ + sseg;
    const unsigned short* Bph = BThi + (size_t)(n0 + srow) * D_ + sseg;
    const unsigned short* Bpl = BTlo + (size_t)(n0 + srow) * D_ + sseg;

    floatx4 acc[4][4];
#pragma unroll
    for (int i = 0; i < 4; i++)
#pragma unroll
        for (int j = 0; j < 4; j++)
#pragma unroll
            for (int r = 0; r < 4; r++) acc[i][j][r] = 0.f;

    uint4 pah[2], pal[2], pbh[2], pbl[2];
    pah[0] = *(const uint4*)(Aph); pah[1] = *(const uint4*)(Aph + 8);
    pal[0] = *(const uint4*)(Apl); pal[1] = *(const uint4*)(Apl + 8);
    pbh[0] = *(const uint4*)(Bph); pbh[1] = *(const uint4*)(Bph + 8);
    pbl[0] = *(const uint4*)(Bpl); pbl[1] = *(const uint4*)(Bpl + 8);

    for (int k0 = 0; k0 < D_; k0 += 32) {
        __syncthreads();
        {
            unsigned short* a = &sAh[srow * AST + sseg];
            unsigned short* b = &sAl[srow * AST + sseg];
            unsigned short* c = &sBh[srow * AST + sseg];
            unsigned short* d = &sBl[srow * AST + sseg];
            *(uint4*)a = pah[0]; *(uint4*)(a + 8) = pah[1];
            *(uint4*)b = pal[0]; *(uint4*)(b + 8) = pal[1];
            *(uint4*)c = pbh[0]; *(uint4*)(c + 8) = pbh[1];
            *(uint4*)d = pbl[0]; *(uint4*)(d + 8) = pbl[1];
        }
        __syncthreads();

        if (k0 + 32 < D_) {
            pah[0] = *(const uint4*)(Aph + k0 + 32); pah[1] = *(const uint4*)(Aph + k0 + 40);
            pal[0] = *(const uint4*)(Apl + k0 + 32); pal[1] = *(const uint4*)(Apl + k0 + 40);
            pbh[0] = *(const uint4*)(Bph + k0 + 32); pbh[1] = *(const uint4*)(Bph + k0 + 40);
            pbl[0] = *(const uint4*)(Bpl + k0 + 32); pbl[1] = *(const uint4*)(Bpl + k0 + 40);
        }

        short8 bhf[4], blf[4];
#pragma unroll
        for (int nb = 0; nb < 4; nb++) {
            const int r = wn + nb * 16 + lm;
            bhf[nb] = *(const short8*)&sBh[r * AST + quad * 8];
            blf[nb] = *(const short8*)&sBl[r * AST + quad * 8];
        }
#pragma unroll
        for (int mb = 0; mb < 4; mb++) {
            const int r = wm + mb * 16 + lm;
            short8 ah = *(const short8*)&sAh[r * AST + quad * 8];
            short8 al = *(const short8*)&sAl[r * AST + quad * 8];
#pragma unroll
            for (int nb = 0; nb < 4; nb++) {
                acc[mb][nb] = __builtin_amdgcn_mfma_f32_16x16x32_bf16(ah, bhf[nb], acc[mb][nb], 0, 0, 0);
                acc[mb][nb] = __builtin_amdgcn_mfma_f32_16x16x32_bf16(al, bhf[nb], acc[mb][nb], 0, 0, 0);
                acc[mb][nb] = __builtin_amdgcn_mfma_f32_16x16x32_bf16(ah, blf[nb], acc[mb][nb], 0, 0, 0);
            }
        }
    }

#pragma unroll
    for (int nb = 0; nb < 4; nb++) {
        const int col = n0 + wn + nb * 16 + lm;
        const float bv = bias[col];
#pragma unroll
        for (int mb = 0; mb < 4; mb++) {
            const int rowb = m0 + wm + mb * 16 + quad * 4;
#pragma unroll
            for (int r = 0; r < 4; r++)
                C[(size_t)(rowb + r) * D_ + col] = acc[mb][nb][r] + bv;
        }
    }
}

// ---------------------------------------------------------------------------
// MFMA flash attention (R6 structure, verified): pre-split bf16 inputs,
// cooperative LDS staging + register prefetch, softmax-lite with deferred
// l-reduction, same-wave P round-trip. Epilogue now writes attn PRE-SPLIT
// into the Q buffers (rows are dead: each block reads its Q rows into regs
// before writing those rows; different heads touch disjoint columns).
// ---------------------------------------------------------------------------
#define PST 72   // u16 row stride (64 data + 8 pad)

__global__ __launch_bounds__(256, 2) void flash_attn_mfma(
    unsigned short* QAhi, unsigned short* QAlo,   // Q in, attn out (aliased)
    const unsigned short* __restrict__ Khi, const unsigned short* __restrict__ Klo,
    const unsigned short* __restrict__ vThi, const unsigned short* __restrict__ vTlo)
{
    __shared__ unsigned short KhiS[64 * PST];
    __shared__ unsigned short KloS[64 * PST];
    __shared__ unsigned short VhiS[64 * PST];
    __shared__ unsigned short VloS[64 * PST];
    __shared__ unsigned short PhS[64 * PST];
    __shared__ unsigned short PlS[64 * PST];

    const int t    = threadIdx.x;
    const int pj   = blockIdx.x;
    const int bh   = blockIdx.y;
    const int b    = bh >> 4, h = bh & 15;
    const int lane = t & 63, w = t >> 6;
    const int lm   = lane & 15, quad = lane >> 4;

    const int srow = t >> 2;
    const int sseg = (t & 3) * 16;

    const unsigned short* Kh_b = Khi + (size_t)(b * S_) * D_ + h * HD + sseg;
    const unsigned short* Kl_b = Klo + (size_t)(b * S_) * D_ + h * HD + sseg;
    const unsigned short* Vh_b = vThi + ((size_t)((b * 16 + h) * 64 + srow)) * S_ + sseg;
    const unsigned short* Vl_b = vTlo + ((size_t)((b * 16 + h) * 64 + srow)) * S_ + sseg;

    for (int phse = 0; phse < 2; phse++) {
        const int qt = phse ? (31 - pj) : pj;
        const int q0 = qt * 64;
        const int ntiles = qt + 1;

        short8 qh[2], ql[2];
        {
            const size_t qoff = (size_t)(b * S_ + q0 + w * 16 + lm) * D_ + h * HD + quad * 8;
            qh[0] = *(const short8*)&QAhi[qoff];
            qh[1] = *(const short8*)&QAhi[qoff + 32];
            ql[0] = *(const short8*)&QAlo[qoff];
            ql[1] = *(const short8*)&QAlo[qoff + 32];
        }

        float lsum[4] = {0.f, 0.f, 0.f, 0.f};
        floatx4 o[4];
#pragma unroll
        for (int nb = 0; nb < 4; nb++)
#pragma unroll
            for (int r = 0; r < 4; r++) o[nb][r] = 0.f;

        uint4 pkh[2], pkl[2], pvh[2], pvl[2];
        {
            const unsigned short* ks = Kh_b + (size_t)srow * D_;
            const unsigned short* ls = Kl_b + (size_t)srow * D_;
            pkh[0] = *(const uint4*)ks;   pkh[1] = *(const uint4*)(ks + 8);
            pkl[0] = *(const uint4*)ls;   pkl[1] = *(const uint4*)(ls + 8);
            pvh[0] = *(const uint4*)Vh_b; pvh[1] = *(const uint4*)(Vh_b + 8);
            pvl[0] = *(const uint4*)Vl_b; pvl[1] = *(const uint4*)(Vl_b + 8);
        }

        for (int kt = 0; kt < ntiles; kt++) {
            __syncthreads();
            {
                unsigned short* d0 = &KhiS[srow * PST + sseg];
                unsigned short* d1 = &KloS[srow * PST + sseg];
                unsigned short* d2 = &VhiS[srow * PST + sseg];
                unsigned short* d3 = &VloS[srow * PST + sseg];
                *(uint4*)d0 = pkh[0]; *(uint4*)(d0 + 8) = pkh[1];
                *(uint4*)d1 = pkl[0]; *(uint4*)(d1 + 8) = pkl[1];
                *(uint4*)d2 = pvh[0]; *(uint4*)(d2 + 8) = pvh[1];
                *(uint4*)d3 = pvl[0]; *(uint4*)(d3 + 8) = pvl[1];
            }
            __syncthreads();

            if (kt + 1 < ntiles) {
                const int k1 = (kt + 1) * 64;
                const unsigned short* ks = Kh_b + (size_t)(k1 + srow) * D_;
                const unsigned short* ls = Kl_b + (size_t)(k1 + srow) * D_;
                pkh[0] = *(const uint4*)ks;          pkh[1] = *(const uint4*)(ks + 8);
                pkl[0] = *(const uint4*)ls;          pkl[1] = *(const uint4*)(ls + 8);
                pvh[0] = *(const uint4*)(Vh_b + k1); pvh[1] = *(const uint4*)(Vh_b + k1 + 8);
                pvl[0] = *(const uint4*)(Vl_b + k1); pvl[1] = *(const uint4*)(Vl_b + k1 + 8);
            }

            floatx4 sa[4];
#pragma unroll
            for (int nb = 0; nb < 4; nb++)
#pragma unroll
                for (int r = 0; r < 4; r++) sa[nb][r] = 0.f;
#pragma unroll
            for (int s = 0; s < 2; s++) {
#pragma unroll
                for (int nb = 0; nb < 4; nb++) {
                    short8 kh = *(const short8*)&KhiS[(nb * 16 + lm) * PST + s * 32 + quad * 8];
                    short8 kl = *(const short8*)&KloS[(nb * 16 + lm) * PST + s * 32 + quad * 8];
                    sa[nb] = __builtin_amdgcn_mfma_f32_16x16x32_bf16(qh[s], kh, sa[nb], 0, 0, 0);
                    sa[nb] = __builtin_amdgcn_mfma_f32_16x16x32_bf16(ql[s], kh, sa[nb], 0, 0, 0);
                    sa[nb] = __builtin_amdgcn_mfma_f32_16x16x32_bf16(qh[s], kl, sa[nb], 0, 0, 0);
                }
            }

            const bool diag = (kt * 64 == q0);
#pragma unroll
            for (int r = 0; r < 4; r++) {
                const int qrow = 16 * w + 4 * quad + r;
#pragma unroll
                for (int nb = 0; nb < 4; nb++) {
                    float p = __expf(sa[nb][r]);
                    if (diag && (16 * nb + lm > qrow)) p = 0.f;
                    lsum[r] += p;
                    unsigned short hh, ll;
                    split2(p, hh, ll);
                    PhS[qrow * PST + 16 * nb + lm] = hh;
                    PlS[qrow * PST + 16 * nb + lm] = ll;
                }
            }

#pragma unroll
            for (int ks = 0; ks < 2; ks++) {
                short8 pf = *(const short8*)&PhS[(16 * w + lm) * PST + ks * 32 + quad * 8];
                short8 pg = *(const short8*)&PlS[(16 * w + lm) * PST + ks * 32 + quad * 8];
#pragma unroll
                for (int nb = 0; nb < 4; nb++) {
                    short8 vhf = *(const short8*)&VhiS[(16 * nb + lm) * PST + ks * 32 + quad * 8];
                    short8 vlf = *(const short8*)&VloS[(16 * nb + lm) * PST + ks * 32 + quad * 8];
                    o[nb] = __builtin_amdgcn_mfma_f32_16x16x32_bf16(pf, vhf, o[nb], 0, 0, 0);
                    o[nb] = __builtin_amdgcn_mfma_f32_16x16x32_bf16(pg, vhf, o[nb], 0, 0, 0);
                    o[nb] = __builtin_amdgcn_mfma_f32_16x16x32_bf16(pf, vlf, o[nb], 0, 0, 0);
                }
            }
        }

        // epilogue: reduce l, normalize, write attn PRE-SPLIT into Q buffers
#pragma unroll
        for (int r = 0; r < 4; r++) {
            float l = lsum[r];
            l += __shfl_xor(l, 1);
            l += __shfl_xor(l, 2);
            l += __shfl_xor(l, 4);
            l += __shfl_xor(l, 8);
            const float inv = 1.f / l;
            const size_t rowoff =
                (size_t)(b * S_ + q0 + 16 * w + 4 * quad + r) * D_ + h * HD + lm;
#pragma unroll
            for (int nb = 0; nb < 4; nb++) {
                unsigned short hh, ll;
                split2(o[nb][r] * inv, hh, ll);
                QAhi[rowoff + 16 * nb] = hh;
                QAlo[rowoff + 16 * nb] = ll;
            }
        }
    }
}

// ---------------------------------------------------------------------------
extern "C" void kernel_launch(void* const* d_in, const int* in_sizes, int n_in,
                              void* d_out, int out_size, void* d_ws, size_t ws_size,
                              hipStream_t stream)
{
    const float* hs     = (const float*)d_in[0];
    const float* attn_w = (const float*)d_in[1];
    const float* attn_b = (const float*)d_in[2];
    const float* proj_w = (const float*)d_in[3];
    const float* proj_b = (const float*)d_in[4];
    float* outp = (float*)d_out;

    const size_t QE = (size_t)M_ * D_;          // 4,194,304
    const size_t WQ = (size_t)D_ * N_QKV;       // 3,145,728
    unsigned short* Qhi   = (unsigned short*)d_ws;       // also attn hi
    unsigned short* Qlo   = Qhi + QE;                    // also attn lo
    unsigned short* Khi   = Qlo + QE;
    unsigned short* Klo   = Khi + QE;
    unsigned short* vThi  = Klo + QE;
    unsigned short* vTlo  = vThi + QE;
    unsigned short* WqThi = vTlo + QE;
    unsigned short* WqTlo = WqThi + WQ;
    unsigned short* WpThi = WqTlo + WQ;
    unsigned short* WpTlo = WpThi + (size_t)D_ * D_;     // total = 64 MB exactly

    dim3 blk(256);
    prep_wT<<<dim3(N_QKV / 64, D_ / 64), blk, 0, stream>>>(attn_w, N_QKV, WqThi, WqTlo);
    prep_wT<<<dim3(D_ / 64, D_ / 64), blk, 0, stream>>>(proj_w, D_, WpThi, WpTlo);
    gemm_qkv<<<dim3(N_QKV / 128, M_ / 128), blk, 0, stream>>>(
        hs, WqThi, WqTlo, attn_b, Qhi, Qlo, Khi, Klo, vThi, vTlo);
    flash_attn_mfma<<<dim3(16, B_ * H_), blk, 0, stream>>>(
        Qhi, Qlo, Khi, Klo, vThi, vTlo);
    gemm_out<<<dim3(D_ / 128, M_ / 128), blk, 0, stream>>>(
        Qhi, Qlo, WpThi, WpTlo, proj_b, outp);
}

// Round 8
// 351.603 us; speedup vs baseline: 1.3968x; 1.3968x over previous
//
#include <hip/hip_runtime.h>
#include <math.h>

#define B_ 2
#define S_ 2048
#define D_ 1024
#define H_ 16
#define HD 64
#define M_ (B_ * S_)     // 4096
#define N_QKV (3 * D_)   // 3072

typedef short short8 __attribute__((ext_vector_type(8)));
typedef float floatx4 __attribute__((ext_vector_type(4)));

static __device__ __forceinline__ unsigned short f2bf_rne(float x) {
    union { float f; unsigned u; } v; v.f = x;
    unsigned r = v.u + 0x7FFFu + ((v.u >> 16) & 1u);
    return (unsigned short)(r >> 16);
}
static __device__ __forceinline__ float bf2f(unsigned short b) {
    union { unsigned u; float f; } v; v.u = ((unsigned)b) << 16;
    return v.f;
}
// RNE split: x = hi + lo + eps, |eps| ~ 2^-17 |x|
static __device__ __forceinline__ void split2(float x, unsigned short& h, unsigned short& l) {
    h = f2bf_rne(x);
    l = f2bf_rne(x - bf2f(h));
}

// async global->LDS DMA, 16 B per lane. LDS dest must be contiguous
// (base + lane*16); global addr is per-lane.
static __device__ __forceinline__ void dma16(const void* g, void* l) {
    __builtin_amdgcn_global_load_lds(
        (const __attribute__((address_space(1))) unsigned int*)g,
        (__attribute__((address_space(3))) unsigned int*)l,
        16, 0, 0);
}

// ---------------------------------------------------------------------------
// prep_wT: W[K=1024][N] fp32 -> WT hi/lo bf16 [N][1024]. (R7-verified)
// ---------------------------------------------------------------------------
__global__ __launch_bounds__(256) void prep_wT(
    const float* __restrict__ W, int N,
    unsigned short* __restrict__ Thi, unsigned short* __restrict__ Tlo)
{
    __shared__ float Ws[64][68];
    const int t  = threadIdx.x;
    const int n0 = blockIdx.x * 64, k0 = blockIdx.y * 64;
    {
        const int kl = t >> 4, nl = (t & 15) * 4;
        const float* src = W + (size_t)(k0 + kl) * N + n0 + nl;
#pragma unroll
        for (int g = 0; g < 4; g++)
            *(float4*)&Ws[kl + g * 16][nl] = *(const float4*)(src + (size_t)g * 16 * N);
    }
    __syncthreads();
    {
        const int nl = t >> 2, ks = (t & 3) * 16;
        short8 h0, h1, l0, l1;
#pragma unroll
        for (int j = 0; j < 8; j++) {
            unsigned short hh, ll;
            split2(Ws[ks + j][nl], hh, ll);
            h0[j] = (short)hh; l0[j] = (short)ll;
        }
#pragma unroll
        for (int j = 0; j < 8; j++) {
            unsigned short hh, ll;
            split2(Ws[ks + 8 + j][nl], hh, ll);
            h1[j] = (short)hh; l1[j] = (short)ll;
        }
        unsigned short* dh = Thi + (size_t)(n0 + nl) * D_ + k0 + ks;
        unsigned short* dl = Tlo + (size_t)(n0 + nl) * D_ + k0 + ks;
        *(short8*)dh = h0; *(short8*)(dh + 8) = h1;
        *(short8*)dl = l0; *(short8*)(dl + 8) = l1;
    }
}

// ---------------------------------------------------------------------------
// QKV GEMM: hs @ W + b. m97-style K-loop: B hi/lo staged by global_load_lds
// DMA (4 instr/wave/iter); A converted in registers (prefetched) + ds_write.
// LDS tiles [128][32] u16 UNPADDED (DMA-contiguous; frag-read pattern hits
// all 32 banks uniformly = b128 floor). Epilogue writes pre-split
// Q*(1/8), K [s][d], V^T [b][h][d][s]. (epilogue R7-verified)
// ---------------------------------------------------------------------------
__global__ __launch_bounds__(256) void gemm_qkv(
    const float* __restrict__ A,
    const unsigned short* __restrict__ BThi, const unsigned short* __restrict__ BTlo,
    const float* __restrict__ bias,
    unsigned short* __restrict__ Qhi, unsigned short* __restrict__ Qlo,
    unsigned short* __restrict__ Khi, unsigned short* __restrict__ Klo,
    unsigned short* __restrict__ vThi, unsigned short* __restrict__ vTlo)
{
    __shared__ unsigned short sAh[128 * 32], sAl[128 * 32];
    __shared__ unsigned short sBh[128 * 32], sBl[128 * 32];

    const int t    = threadIdx.x;
    const int m0   = blockIdx.y * 128, n0 = blockIdx.x * 128;
    const int lane = t & 63, wave = t >> 6;
    const int lm   = lane & 15, quad = lane >> 4;
    const int wm   = (wave >> 1) * 64, wn = (wave & 1) * 64;

    // A staging map (register path): row, 16-elem k-group
    const int srow = t >> 1, sseg = (t & 1) * 16;
    const float* Ap = A + (size_t)(m0 + srow) * D_ + sseg;

    // B DMA map: wave covers rows wave*32 + j*16 + lane/4, col (lane&3)*8
    const int lrow = lane >> 2, lcol = (lane & 3) * 8;
    const unsigned short* gBh0 = BThi + (size_t)(n0 + wave * 32 + lrow) * D_ + lcol;
    const unsigned short* gBl0 = BTlo + (size_t)(n0 + wave * 32 + lrow) * D_ + lcol;
    unsigned short* lBh0 = sBh + wave * 1024 + lane * 8;
    unsigned short* lBl0 = sBl + wave * 1024 + lane * 8;

    floatx4 acc[4][4];
#pragma unroll
    for (int i = 0; i < 4; i++)
#pragma unroll
        for (int j = 0; j < 4; j++)
#pragma unroll
            for (int r = 0; r < 4; r++) acc[i][j][r] = 0.f;

    float4 af[4];
    af[0] = *(const float4*)(Ap);     af[1] = *(const float4*)(Ap + 4);
    af[2] = *(const float4*)(Ap + 8); af[3] = *(const float4*)(Ap + 12);

    for (int k0 = 0; k0 < D_; k0 += 32) {
        // convert prefetched A in registers
        short8 ah0, ah1, al0, al1;
#pragma unroll
        for (int g = 0; g < 4; g++) {
            float xs[4] = {af[g].x, af[g].y, af[g].z, af[g].w};
#pragma unroll
            for (int e = 0; e < 4; e++) {
                unsigned short hh, ll;
                split2(xs[e], hh, ll);
                if (g < 2) { ah0[g * 4 + e] = (short)hh; al0[g * 4 + e] = (short)ll; }
                else       { ah1[(g - 2) * 4 + e] = (short)hh; al1[(g - 2) * 4 + e] = (short)ll; }
            }
        }
        __syncthreads();   // consumers of previous tile done
        {
            unsigned short* a = &sAh[srow * 32 + sseg];
            unsigned short* b = &sAl[srow * 32 + sseg];
            *(short8*)a = ah0; *(short8*)(a + 8) = ah1;
            *(short8*)b = al0; *(short8*)(b + 8) = al1;
        }
        // B tiles via async DMA (arrive by the next barrier's vmcnt drain)
        dma16(gBh0 + k0, lBh0);
        dma16(gBh0 + (size_t)16 * D_ + k0, lBh0 + 512);
        dma16(gBl0 + k0, lBl0);
        dma16(gBl0 + (size_t)16 * D_ + k0, lBl0 + 512);
        __syncthreads();   // vmcnt(0)+lgkmcnt(0): tile fully staged

        if (k0 + 32 < D_) {   // prefetch next A (hidden behind MFMAs)
            const float* an = Ap + k0 + 32;
            af[0] = *(const float4*)(an);     af[1] = *(const float4*)(an + 4);
            af[2] = *(const float4*)(an + 8); af[3] = *(const float4*)(an + 12);
        }

        short8 bhf[4], blf[4];
#pragma unroll
        for (int nb = 0; nb < 4; nb++) {
            const int r = wn + nb * 16 + lm;
            bhf[nb] = *(const short8*)&sBh[r * 32 + quad * 8];
            blf[nb] = *(const short8*)&sBl[r * 32 + quad * 8];
        }
#pragma unroll
        for (int mb = 0; mb < 4; mb++) {
            const int r = wm + mb * 16 + lm;
            short8 ah = *(const short8*)&sAh[r * 32 + quad * 8];
            short8 al = *(const short8*)&sAl[r * 32 + quad * 8];
#pragma unroll
            for (int nb = 0; nb < 4; nb++) {
                acc[mb][nb] = __builtin_amdgcn_mfma_f32_16x16x32_bf16(ah, bhf[nb], acc[mb][nb], 0, 0, 0);
                acc[mb][nb] = __builtin_amdgcn_mfma_f32_16x16x32_bf16(al, bhf[nb], acc[mb][nb], 0, 0, 0);
                acc[mb][nb] = __builtin_amdgcn_mfma_f32_16x16x32_bf16(ah, blf[nb], acc[mb][nb], 0, 0, 0);
            }
        }
    }

    const int nmode = n0 >> 10;   // 0=Q, 1=K, 2=V (block-uniform)
    if (nmode == 0) {
#pragma unroll
        for (int nb = 0; nb < 4; nb++) {
            const int c = n0 + wn + nb * 16 + lm;
            const float bv = bias[c];
#pragma unroll
            for (int mb = 0; mb < 4; mb++) {
                const int rowb = m0 + wm + mb * 16 + quad * 4;
#pragma unroll
                for (int r = 0; r < 4; r++) {
                    unsigned short hh, ll;
                    split2((acc[mb][nb][r] + bv) * 0.125f, hh, ll);
                    Qhi[(size_t)(rowb + r) * D_ + c] = hh;
                    Qlo[(size_t)(rowb + r) * D_ + c] = ll;
                }
            }
        }
    } else if (nmode == 1) {
#pragma unroll
        for (int nb = 0; nb < 4; nb++) {
            const int c = n0 + wn + nb * 16 + lm;
            const float bv = bias[c];
            const int cq = c - 1024;
#pragma unroll
            for (int mb = 0; mb < 4; mb++) {
                const int rowb = m0 + wm + mb * 16 + quad * 4;
#pragma unroll
                for (int r = 0; r < 4; r++) {
                    unsigned short hh, ll;
                    split2(acc[mb][nb][r] + bv, hh, ll);
                    Khi[(size_t)(rowb + r) * D_ + cq] = hh;
                    Klo[(size_t)(rowb + r) * D_ + cq] = ll;
                }
            }
        }
    } else {
#pragma unroll
        for (int nb = 0; nb < 4; nb++) {
            const int c = n0 + wn + nb * 16 + lm;
            const float bv = bias[c];
            const int cq = c - 2048;
            const int hh_ = cq >> 6, dd = cq & 63;
#pragma unroll
            for (int mb = 0; mb < 4; mb++) {
                const int rowb = m0 + wm + mb * 16 + quad * 4;
                const int bb = rowb >> 11, ss = rowb & 2047;
                unsigned short hv[4], lv[4];
#pragma unroll
                for (int r = 0; r < 4; r++)
                    split2(acc[mb][nb][r] + bv, hv[r], lv[r]);
                const size_t idx = ((size_t)((bb * 16 + hh_) * 64 + dd)) * S_ + ss;
                *(uint2*)&vThi[idx] = make_uint2((unsigned)hv[0] | ((unsigned)hv[1] << 16),
                                                 (unsigned)hv[2] | ((unsigned)hv[3] << 16));
                *(uint2*)&vTlo[idx] = make_uint2((unsigned)lv[0] | ((unsigned)lv[1] << 16),
                                                 (unsigned)lv[2] | ((unsigned)lv[3] << 16));
            }
        }
    }
}

// ---------------------------------------------------------------------------
// Proj GEMM: attn(pre-split) @ projW^T(pre-split) + bias -> fp32.
// 64x64 tiles (1024 blocks = 4/CU for TLP), fully-DMA staging, zero VALU
// in the K-loop. Wave w owns rows 16w..16w+15, all 64 cols (acc[4]).
// ---------------------------------------------------------------------------
__global__ __launch_bounds__(256) void gemm_out(
    const unsigned short* __restrict__ Ahi, const unsigned short* __restrict__ Alo,
    const unsigned short* __restrict__ BThi, const unsigned short* __restrict__ BTlo,
    const float* __restrict__ bias, float* __restrict__ C)
{
    __shared__ unsigned short sAh[64 * 32], sAl[64 * 32];
    __shared__ unsigned short sBh[64 * 32], sBl[64 * 32];

    const int t    = threadIdx.x;
    const int m0   = blockIdx.y * 64, n0 = blockIdx.x * 64;
    const int lane = t & 63, wave = t >> 6;
    const int lm   = lane & 15, quad = lane >> 4;

    // DMA map: instr i = wave covers rows wave*16 + lane/4, col (lane&3)*8
    const int lrow = lane >> 2, lcol = (lane & 3) * 8;
    const unsigned short* gAh = Ahi + (size_t)(m0 + wave * 16 + lrow) * D_ + lcol;
    const unsigned short* gAl = Alo + (size_t)(m0 + wave * 16 + lrow) * D_ + lcol;
    const unsigned short* gBh = BThi + (size_t)(n0 + wave * 16 + lrow) * D_ + lcol;
    const unsigned short* gBl = BTlo + (size_t)(n0 + wave * 16 + lrow) * D_ + lcol;
    unsigned short* lAh = sAh + wave * 512 + lane * 8;
    unsigned short* lAl = sAl + wave * 512 + lane * 8;
    unsigned short* lBh = sBh + wave * 512 + lane * 8;
    unsigned short* lBl = sBl + wave * 512 + lane * 8;

    floatx4 acc[4];
#pragma unroll
    for (int j = 0; j < 4; j++)
#pragma unroll
        for (int r = 0; r < 4; r++) acc[j][r] = 0.f;

    for (int k0 = 0; k0 < D_; k0 += 32) {
        __syncthreads();   // prev consumers done
        dma16(gAh + k0, lAh);
        dma16(gAl + k0, lAl);
        dma16(gBh + k0, lBh);
        dma16(gBl + k0, lBl);
        __syncthreads();   // vmcnt(0): staged

        short8 ah = *(const short8*)&sAh[(wave * 16 + lm) * 32 + quad * 8];
        short8 al = *(const short8*)&sAl[(wave * 16 + lm) * 32 + quad * 8];
#pragma unroll
        for (int nb = 0; nb < 4; nb++) {
            short8 bh = *(const short8*)&sBh[(nb * 16 + lm) * 32 + quad * 8];
            short8 bl = *(const short8*)&sBl[(nb * 16 + lm) * 32 + quad * 8];
            acc[nb] = __builtin_amdgcn_mfma_f32_16x16x32_bf16(ah, bh, acc[nb], 0, 0, 0);
            acc[nb] = __builtin_amdgcn_mfma_f32_16x16x32_bf16(al, bh, acc[nb], 0, 0, 0);
            acc[nb] = __builtin_amdgcn_mfma_f32_16x16x32_bf16(ah, bl, acc[nb], 0, 0, 0);
        }
    }

#pragma unroll
    for (int nb = 0; nb < 4; nb++) {
        const int col = n0 + nb * 16 + lm;
        const float bv = bias[col];
#pragma unroll
        for (int r = 0; r < 4; r++) {
            const int row = m0 + wave * 16 + quad * 4 + r;
            C[(size_t)row * D_ + col] = acc[nb][r] + bv;
        }
    }
}

// ---------------------------------------------------------------------------
// MFMA flash attention (R6/R7-verified): pre-split bf16 inputs, cooperative
// LDS staging + register prefetch, softmax-lite with deferred l-reduction,
// same-wave P round-trip. Epilogue writes attn PRE-SPLIT into Q buffers.
// ---------------------------------------------------------------------------
#define PST 72   // u16 row stride (64 data + 8 pad)

__global__ __launch_bounds__(256, 2) void flash_attn_mfma(
    unsigned short* QAhi, unsigned short* QAlo,   // Q in, attn out (aliased)
    const unsigned short* __restrict__ Khi, const unsigned short* __restrict__ Klo,
    const unsigned short* __restrict__ vThi, const unsigned short* __restrict__ vTlo)
{
    __shared__ unsigned short KhiS[64 * PST];
    __shared__ unsigned short KloS[64 * PST];
    __shared__ unsigned short VhiS[64 * PST];
    __shared__ unsigned short VloS[64 * PST];
    __shared__ unsigned short PhS[64 * PST];
    __shared__ unsigned short PlS[64 * PST];

    const int t    = threadIdx.x;
    const int pj   = blockIdx.x;
    const int bh   = blockIdx.y;
    const int b    = bh >> 4, h = bh & 15;
    const int lane = t & 63, w = t >> 6;
    const int lm   = lane & 15, quad = lane >> 4;

    const int srow = t >> 2;
    const int sseg = (t & 3) * 16;

    const unsigned short* Kh_b = Khi + (size_t)(b * S_) * D_ + h * HD + sseg;
    const unsigned short* Kl_b = Klo + (size_t)(b * S_) * D_ + h * HD + sseg;
    const unsigned short* Vh_b = vThi + ((size_t)((b * 16 + h) * 64 + srow)) * S_ + sseg;
    const unsigned short* Vl_b = vTlo + ((size_t)((b * 16 + h) * 64 + srow)) * S_ + sseg;

    for (int phse = 0; phse < 2; phse++) {
        const int qt = phse ? (31 - pj) : pj;
        const int q0 = qt * 64;
        const int ntiles = qt + 1;

        short8 qh[2], ql[2];
        {
            const size_t qoff = (size_t)(b * S_ + q0 + w * 16 + lm) * D_ + h * HD + quad * 8;
            qh[0] = *(const short8*)&QAhi[qoff];
            qh[1] = *(const short8*)&QAhi[qoff + 32];
            ql[0] = *(const short8*)&QAlo[qoff];
            ql[1] = *(const short8*)&QAlo[qoff + 32];
        }

        float lsum[4] = {0.f, 0.f, 0.f, 0.f};
        floatx4 o[4];
#pragma unroll
        for (int nb = 0; nb < 4; nb++)
#pragma unroll
            for (int r = 0; r < 4; r++) o[nb][r] = 0.f;

        uint4 pkh[2], pkl[2], pvh[2], pvl[2];
        {
            const unsigned short* ks = Kh_b + (size_t)srow * D_;
            const unsigned short* ls = Kl_b + (size_t)srow * D_;
            pkh[0] = *(const uint4*)ks;   pkh[1] = *(const uint4*)(ks + 8);
            pkl[0] = *(const uint4*)ls;   pkl[1] = *(const uint4*)(ls + 8);
            pvh[0] = *(const uint4*)Vh_b; pvh[1] = *(const uint4*)(Vh_b + 8);
            pvl[0] = *(const uint4*)Vl_b; pvl[1] = *(const uint4*)(Vl_b + 8);
        }

        for (int kt = 0; kt < ntiles; kt++) {
            __syncthreads();
            {
                unsigned short* d0 = &KhiS[srow * PST + sseg];
                unsigned short* d1 = &KloS[srow * PST + sseg];
                unsigned short* d2 = &VhiS[srow * PST + sseg];
                unsigned short* d3 = &VloS[srow * PST + sseg];
                *(uint4*)d0 = pkh[0]; *(uint4*)(d0 + 8) = pkh[1];
                *(uint4*)d1 = pkl[0]; *(uint4*)(d1 + 8) = pkl[1];
                *(uint4*)d2 = pvh[0]; *(uint4*)(d2 + 8) = pvh[1];
                *(uint4*)d3 = pvl[0]; *(uint4*)(d3 + 8) = pvl[1];
            }
            __syncthreads();

            if (kt + 1 < ntiles) {
                const int k1 = (kt + 1) * 64;
                const unsigned short* ks = Kh_b + (size_t)(k1 + srow) * D_;
                const unsigned short* ls = Kl_b + (size_t)(k1 + srow) * D_;
                pkh[0] = *(const uint4*)ks;          pkh[1] = *(const uint4*)(ks + 8);
                pkl[0] = *(const uint4*)ls;          pkl[1] = *(const uint4*)(ls + 8);
                pvh[0] = *(const uint4*)(Vh_b + k1); pvh[1] = *(const uint4*)(Vh_b + k1 + 8);
                pvl[0] = *(const uint4*)(Vl_b + k1); pvl[1] = *(const uint4*)(Vl_b + k1 + 8);
            }

            floatx4 sa[4];
#pragma unroll
            for (int nb = 0; nb < 4; nb++)
#pragma unroll
                for (int r = 0; r < 4; r++) sa[nb][r] = 0.f;
#pragma unroll
            for (int s = 0; s < 2; s++) {
#pragma unroll
                for (int nb = 0; nb < 4; nb++) {
                    short8 kh = *(const short8*)&KhiS[(nb * 16 + lm) * PST + s * 32 + quad * 8];
                    short8 kl = *(const short8*)&KloS[(nb * 16 + lm) * PST + s * 32 + quad * 8];
                    sa[nb] = __builtin_amdgcn_mfma_f32_16x16x32_bf16(qh[s], kh, sa[nb], 0, 0, 0);
                    sa[nb] = __builtin_amdgcn_mfma_f32_16x16x32_bf16(ql[s], kh, sa[nb], 0, 0, 0);
                    sa[nb] = __builtin_amdgcn_mfma_f32_16x16x32_bf16(qh[s], kl, sa[nb], 0, 0, 0);
                }
            }

            const bool diag = (kt * 64 == q0);
#pragma unroll
            for (int r = 0; r < 4; r++) {
                const int qrow = 16 * w + 4 * quad + r;
#pragma unroll
                for (int nb = 0; nb < 4; nb++) {
                    float p = __expf(sa[nb][r]);
                    if (diag && (16 * nb + lm > qrow)) p = 0.f;
                    lsum[r] += p;
                    unsigned short hh, ll;
                    split2(p, hh, ll);
                    PhS[qrow * PST + 16 * nb + lm] = hh;
                    PlS[qrow * PST + 16 * nb + lm] = ll;
                }
            }

#pragma unroll
            for (int ks = 0; ks < 2; ks++) {
                short8 pf = *(const short8*)&PhS[(16 * w + lm) * PST + ks * 32 + quad * 8];
                short8 pg = *(const short8*)&PlS[(16 * w + lm) * PST + ks * 32 + quad * 8];
#pragma unroll
                for (int nb = 0; nb < 4; nb++) {
                    short8 vhf = *(const short8*)&VhiS[(16 * nb + lm) * PST + ks * 32 + quad * 8];
                    short8 vlf = *(const short8*)&VloS[(16 * nb + lm) * PST + ks * 32 + quad * 8];
                    o[nb] = __builtin_amdgcn_mfma_f32_16x16x32_bf16(pf, vhf, o[nb], 0, 0, 0);
                    o[nb] = __builtin_amdgcn_mfma_f32_16x16x32_bf16(pg, vhf, o[nb], 0, 0, 0);
                    o[nb] = __builtin_amdgcn_mfma_f32_16x16x32_bf16(pf, vlf, o[nb], 0, 0, 0);
                }
            }
        }

        // epilogue: reduce l, normalize, write attn PRE-SPLIT into Q buffers
#pragma unroll
        for (int r = 0; r < 4; r++) {
            float l = lsum[r];
            l += __shfl_xor(l, 1);
            l += __shfl_xor(l, 2);
            l += __shfl_xor(l, 4);
            l += __shfl_xor(l, 8);
            const float inv = 1.f / l;
            const size_t rowoff =
                (size_t)(b * S_ + q0 + 16 * w + 4 * quad + r) * D_ + h * HD + lm;
#pragma unroll
            for (int nb = 0; nb < 4; nb++) {
                unsigned short hh, ll;
                split2(o[nb][r] * inv, hh, ll);
                QAhi[rowoff + 16 * nb] = hh;
                QAlo[rowoff + 16 * nb] = ll;
            }
        }
    }
}

// ---------------------------------------------------------------------------
extern "C" void kernel_launch(void* const* d_in, const int* in_sizes, int n_in,
                              void* d_out, int out_size, void* d_ws, size_t ws_size,
                              hipStream_t stream)
{
    const float* hs     = (const float*)d_in[0];
    const float* attn_w = (const float*)d_in[1];
    const float* attn_b = (const float*)d_in[2];
    const float* proj_w = (const float*)d_in[3];
    const float* proj_b = (const float*)d_in[4];
    float* outp = (float*)d_out;

    const size_t QE = (size_t)M_ * D_;          // 4,194,304
    const size_t WQ = (size_t)D_ * N_QKV;       // 3,145,728
    unsigned short* Qhi   = (unsigned short*)d_ws;       // also attn hi
    unsigned short* Qlo   = Qhi + QE;                    // also attn lo
    unsigned short* Khi   = Qlo + QE;
    unsigned short* Klo   = Khi + QE;
    unsigned short* vThi  = Klo + QE;
    unsigned short* vTlo  = vThi + QE;
    unsigned short* WqThi = vTlo + QE;
    unsigned short* WqTlo = WqThi + WQ;
    unsigned short* WpThi = WqTlo + WQ;
    unsigned short* WpTlo = WpThi + (size_t)D_ * D_;     // total = 64 MB exactly

    dim3 blk(256);
    prep_wT<<<dim3(N_QKV / 64, D_ / 64), blk, 0, stream>>>(attn_w, N_QKV, WqThi, WqTlo);
    prep_wT<<<dim3(D_ / 64, D_ / 64), blk, 0, stream>>>(proj_w, D_, WpThi, WpTlo);
    gemm_qkv<<<dim3(N_QKV / 128, M_ / 128), blk, 0, stream>>>(
        hs, WqThi, WqTlo, attn_b, Qhi, Qlo, Khi, Klo, vThi, vTlo);
    flash_attn_mfma<<<dim3(16, B_ * H_), blk, 0, stream>>>(
        Qhi, Qlo, Khi, Klo, vThi, vTlo);
    gemm_out<<<dim3(D_ / 64, M_ / 64), blk, 0, stream>>>(
        Qhi, Qlo, WpThi, WpTlo, proj_b, outp);
}

// Round 9
// 315.510 us; speedup vs baseline: 1.5566x; 1.1144x over previous
//
#include <hip/hip_runtime.h>
#include <math.h>

#define B_ 2
#define S_ 2048
#define D_ 1024
#define H_ 16
#define HD 64
#define M_ (B_ * S_)     // 4096
#define N_QKV (3 * D_)   // 3072

typedef short short8 __attribute__((ext_vector_type(8)));
typedef float floatx4 __attribute__((ext_vector_type(4)));

static __device__ __forceinline__ unsigned short f2bf_rne(float x) {
    union { float f; unsigned u; } v; v.f = x;
    unsigned r = v.u + 0x7FFFu + ((v.u >> 16) & 1u);
    return (unsigned short)(r >> 16);
}
static __device__ __forceinline__ float bf2f(unsigned short b) {
    union { unsigned u; float f; } v; v.u = ((unsigned)b) << 16;
    return v.f;
}
// RNE split: x = hi + lo + eps, |eps| ~ 2^-17 |x|
static __device__ __forceinline__ void split2(float x, unsigned short& h, unsigned short& l) {
    h = f2bf_rne(x);
    l = f2bf_rne(x - bf2f(h));
}

// async global->LDS DMA, 16 B per lane (dest = wave-uniform base + lane*16)
static __device__ __forceinline__ void dma16(const void* g, void* l) {
    __builtin_amdgcn_global_load_lds(
        (const __attribute__((address_space(1))) unsigned int*)g,
        (__attribute__((address_space(3))) unsigned int*)l,
        16, 0, 0);
}

// ---------------------------------------------------------------------------
// prep_wT: W[K=1024][N] fp32 -> WT hi/lo bf16 [N][1024]. (R7/R8-verified)
// ---------------------------------------------------------------------------
__global__ __launch_bounds__(256) void prep_wT(
    const float* __restrict__ W, int N,
    unsigned short* __restrict__ Thi, unsigned short* __restrict__ Tlo)
{
    __shared__ float Ws[64][68];
    const int t  = threadIdx.x;
    const int n0 = blockIdx.x * 64, k0 = blockIdx.y * 64;
    {
        const int kl = t >> 4, nl = (t & 15) * 4;
        const float* src = W + (size_t)(k0 + kl) * N + n0 + nl;
#pragma unroll
        for (int g = 0; g < 4; g++)
            *(float4*)&Ws[kl + g * 16][nl] = *(const float4*)(src + (size_t)g * 16 * N);
    }
    __syncthreads();
    {
        const int nl = t >> 2, ks = (t & 3) * 16;
        short8 h0, h1, l0, l1;
#pragma unroll
        for (int j = 0; j < 8; j++) {
            unsigned short hh, ll;
            split2(Ws[ks + j][nl], hh, ll);
            h0[j] = (short)hh; l0[j] = (short)ll;
        }
#pragma unroll
        for (int j = 0; j < 8; j++) {
            unsigned short hh, ll;
            split2(Ws[ks + 8 + j][nl], hh, ll);
            h1[j] = (short)hh; l1[j] = (short)ll;
        }
        unsigned short* dh = Thi + (size_t)(n0 + nl) * D_ + k0 + ks;
        unsigned short* dl = Tlo + (size_t)(n0 + nl) * D_ + k0 + ks;
        *(short8*)dh = h0; *(short8*)(dh + 8) = h1;
        *(short8*)dl = l0; *(short8*)(dl + 8) = l1;
    }
}

// ---------------------------------------------------------------------------
// QKV GEMM (R8-verified): hs @ W + b; B hi/lo via global_load_lds DMA,
// A register-converted + ds_write. Epilogue writes pre-split Q*(1/8),
// K [s][d], V^T [b][h][d][s].
// ---------------------------------------------------------------------------
__global__ __launch_bounds__(256) void gemm_qkv(
    const float* __restrict__ A,
    const unsigned short* __restrict__ BThi, const unsigned short* __restrict__ BTlo,
    const float* __restrict__ bias,
    unsigned short* __restrict__ Qhi, unsigned short* __restrict__ Qlo,
    unsigned short* __restrict__ Khi, unsigned short* __restrict__ Klo,
    unsigned short* __restrict__ vThi, unsigned short* __restrict__ vTlo)
{
    __shared__ unsigned short sAh[128 * 32], sAl[128 * 32];
    __shared__ unsigned short sBh[128 * 32], sBl[128 * 32];

    const int t    = threadIdx.x;
    const int m0   = blockIdx.y * 128, n0 = blockIdx.x * 128;
    const int lane = t & 63, wave = t >> 6;
    const int lm   = lane & 15, quad = lane >> 4;
    const int wm   = (wave >> 1) * 64, wn = (wave & 1) * 64;

    const int srow = t >> 1, sseg = (t & 1) * 16;
    const float* Ap = A + (size_t)(m0 + srow) * D_ + sseg;

    const int lrow = lane >> 2, lcol = (lane & 3) * 8;
    const unsigned short* gBh0 = BThi + (size_t)(n0 + wave * 32 + lrow) * D_ + lcol;
    const unsigned short* gBl0 = BTlo + (size_t)(n0 + wave * 32 + lrow) * D_ + lcol;
    unsigned short* lBh0 = sBh + wave * 1024 + lane * 8;
    unsigned short* lBl0 = sBl + wave * 1024 + lane * 8;

    floatx4 acc[4][4];
#pragma unroll
    for (int i = 0; i < 4; i++)
#pragma unroll
        for (int j = 0; j < 4; j++)
#pragma unroll
            for (int r = 0; r < 4; r++) acc[i][j][r] = 0.f;

    float4 af[4];
    af[0] = *(const float4*)(Ap);     af[1] = *(const float4*)(Ap + 4);
    af[2] = *(const float4*)(Ap + 8); af[3] = *(const float4*)(Ap + 12);

    for (int k0 = 0; k0 < D_; k0 += 32) {
        short8 ah0, ah1, al0, al1;
#pragma unroll
        for (int g = 0; g < 4; g++) {
            float xs[4] = {af[g].x, af[g].y, af[g].z, af[g].w};
#pragma unroll
            for (int e = 0; e < 4; e++) {
                unsigned short hh, ll;
                split2(xs[e], hh, ll);
                if (g < 2) { ah0[g * 4 + e] = (short)hh; al0[g * 4 + e] = (short)ll; }
                else       { ah1[(g - 2) * 4 + e] = (short)hh; al1[(g - 2) * 4 + e] = (short)ll; }
            }
        }
        __syncthreads();
        {
            unsigned short* a = &sAh[srow * 32 + sseg];
            unsigned short* b = &sAl[srow * 32 + sseg];
            *(short8*)a = ah0; *(short8*)(a + 8) = ah1;
            *(short8*)b = al0; *(short8*)(b + 8) = al1;
        }
        dma16(gBh0 + k0, lBh0);
        dma16(gBh0 + (size_t)16 * D_ + k0, lBh0 + 512);
        dma16(gBl0 + k0, lBl0);
        dma16(gBl0 + (size_t)16 * D_ + k0, lBl0 + 512);
        __syncthreads();

        if (k0 + 32 < D_) {
            const float* an = Ap + k0 + 32;
            af[0] = *(const float4*)(an);     af[1] = *(const float4*)(an + 4);
            af[2] = *(const float4*)(an + 8); af[3] = *(const float4*)(an + 12);
        }

        short8 bhf[4], blf[4];
#pragma unroll
        for (int nb = 0; nb < 4; nb++) {
            const int r = wn + nb * 16 + lm;
            bhf[nb] = *(const short8*)&sBh[r * 32 + quad * 8];
            blf[nb] = *(const short8*)&sBl[r * 32 + quad * 8];
        }
#pragma unroll
        for (int mb = 0; mb < 4; mb++) {
            const int r = wm + mb * 16 + lm;
            short8 ah = *(const short8*)&sAh[r * 32 + quad * 8];
            short8 al = *(const short8*)&sAl[r * 32 + quad * 8];
#pragma unroll
            for (int nb = 0; nb < 4; nb++) {
                acc[mb][nb] = __builtin_amdgcn_mfma_f32_16x16x32_bf16(ah, bhf[nb], acc[mb][nb], 0, 0, 0);
                acc[mb][nb] = __builtin_amdgcn_mfma_f32_16x16x32_bf16(al, bhf[nb], acc[mb][nb], 0, 0, 0);
                acc[mb][nb] = __builtin_amdgcn_mfma_f32_16x16x32_bf16(ah, blf[nb], acc[mb][nb], 0, 0, 0);
            }
        }
    }

    const int nmode = n0 >> 10;
    if (nmode == 0) {
#pragma unroll
        for (int nb = 0; nb < 4; nb++) {
            const int c = n0 + wn + nb * 16 + lm;
            const float bv = bias[c];
#pragma unroll
            for (int mb = 0; mb < 4; mb++) {
                const int rowb = m0 + wm + mb * 16 + quad * 4;
#pragma unroll
                for (int r = 0; r < 4; r++) {
                    unsigned short hh, ll;
                    split2((acc[mb][nb][r] + bv) * 0.125f, hh, ll);
                    Qhi[(size_t)(rowb + r) * D_ + c] = hh;
                    Qlo[(size_t)(rowb + r) * D_ + c] = ll;
                }
            }
        }
    } else if (nmode == 1) {
#pragma unroll
        for (int nb = 0; nb < 4; nb++) {
            const int c = n0 + wn + nb * 16 + lm;
            const float bv = bias[c];
            const int cq = c - 1024;
#pragma unroll
            for (int mb = 0; mb < 4; mb++) {
                const int rowb = m0 + wm + mb * 16 + quad * 4;
#pragma unroll
                for (int r = 0; r < 4; r++) {
                    unsigned short hh, ll;
                    split2(acc[mb][nb][r] + bv, hh, ll);
                    Khi[(size_t)(rowb + r) * D_ + cq] = hh;
                    Klo[(size_t)(rowb + r) * D_ + cq] = ll;
                }
            }
        }
    } else {
#pragma unroll
        for (int nb = 0; nb < 4; nb++) {
            const int c = n0 + wn + nb * 16 + lm;
            const float bv = bias[c];
            const int cq = c - 2048;
            const int hh_ = cq >> 6, dd = cq & 63;
#pragma unroll
            for (int mb = 0; mb < 4; mb++) {
                const int rowb = m0 + wm + mb * 16 + quad * 4;
                const int bb = rowb >> 11, ss = rowb & 2047;
                unsigned short hv[4], lv[4];
#pragma unroll
                for (int r = 0; r < 4; r++)
                    split2(acc[mb][nb][r] + bv, hv[r], lv[r]);
                const size_t idx = ((size_t)((bb * 16 + hh_) * 64 + dd)) * S_ + ss;
                *(uint2*)&vThi[idx] = make_uint2((unsigned)hv[0] | ((unsigned)hv[1] << 16),
                                                 (unsigned)hv[2] | ((unsigned)hv[3] << 16));
                *(uint2*)&vTlo[idx] = make_uint2((unsigned)lv[0] | ((unsigned)lv[1] << 16),
                                                 (unsigned)lv[2] | ((unsigned)lv[3] << 16));
            }
        }
    }
}

// ---------------------------------------------------------------------------
// Proj GEMM (R8-verified): 64x64 tiles, fully-DMA staging, zero K-loop VALU.
// ---------------------------------------------------------------------------
__global__ __launch_bounds__(256) void gemm_out(
    const unsigned short* __restrict__ Ahi, const unsigned short* __restrict__ Alo,
    const unsigned short* __restrict__ BThi, const unsigned short* __restrict__ BTlo,
    const float* __restrict__ bias, float* __restrict__ C)
{
    __shared__ unsigned short sAh[64 * 32], sAl[64 * 32];
    __shared__ unsigned short sBh[64 * 32], sBl[64 * 32];

    const int t    = threadIdx.x;
    const int m0   = blockIdx.y * 64, n0 = blockIdx.x * 64;
    const int lane = t & 63, wave = t >> 6;
    const int lm   = lane & 15, quad = lane >> 4;

    const int lrow = lane >> 2, lcol = (lane & 3) * 8;
    const unsigned short* gAh = Ahi + (size_t)(m0 + wave * 16 + lrow) * D_ + lcol;
    const unsigned short* gAl = Alo + (size_t)(m0 + wave * 16 + lrow) * D_ + lcol;
    const unsigned short* gBh = BThi + (size_t)(n0 + wave * 16 + lrow) * D_ + lcol;
    const unsigned short* gBl = BTlo + (size_t)(n0 + wave * 16 + lrow) * D_ + lcol;
    unsigned short* lAh = sAh + wave * 512 + lane * 8;
    unsigned short* lAl = sAl + wave * 512 + lane * 8;
    unsigned short* lBh = sBh + wave * 512 + lane * 8;
    unsigned short* lBl = sBl + wave * 512 + lane * 8;

    floatx4 acc[4];
#pragma unroll
    for (int j = 0; j < 4; j++)
#pragma unroll
        for (int r = 0; r < 4; r++) acc[j][r] = 0.f;

    for (int k0 = 0; k0 < D_; k0 += 32) {
        __syncthreads();
        dma16(gAh + k0, lAh);
        dma16(gAl + k0, lAl);
        dma16(gBh + k0, lBh);
        dma16(gBl + k0, lBl);
        __syncthreads();

        short8 ah = *(const short8*)&sAh[(wave * 16 + lm) * 32 + quad * 8];
        short8 al = *(const short8*)&sAl[(wave * 16 + lm) * 32 + quad * 8];
#pragma unroll
        for (int nb = 0; nb < 4; nb++) {
            short8 bh = *(const short8*)&sBh[(nb * 16 + lm) * 32 + quad * 8];
            short8 bl = *(const short8*)&sBl[(nb * 16 + lm) * 32 + quad * 8];
            acc[nb] = __builtin_amdgcn_mfma_f32_16x16x32_bf16(ah, bh, acc[nb], 0, 0, 0);
            acc[nb] = __builtin_amdgcn_mfma_f32_16x16x32_bf16(al, bh, acc[nb], 0, 0, 0);
            acc[nb] = __builtin_amdgcn_mfma_f32_16x16x32_bf16(ah, bl, acc[nb], 0, 0, 0);
        }
    }

#pragma unroll
    for (int nb = 0; nb < 4; nb++) {
        const int col = n0 + nb * 16 + lm;
        const float bv = bias[col];
#pragma unroll
        for (int r = 0; r < 4; r++) {
            const int row = m0 + wave * 16 + quad * 4 + r;
            C[(size_t)row * D_ + col] = acc[nb][r] + bv;
        }
    }
}

// ---------------------------------------------------------------------------
// MFMA flash attention, 128-row Q super-tile / 512 threads (8 waves):
// each staged 64-row K/V tile serves 128 Q rows (half the staging + half the
// global K/V traffic per unit work vs R8). Wave w owns rows 16w..16w+15;
// per-wave causal skip past its diagonal tile (wdiag). Softmax-lite +
// deferred l-reduction; same-wave P round-trip; epilogue writes attn
// PRE-SPLIT into Q buffers. Block pj pairs q-tiles pj and 15-pj (36 k-iters).
// ---------------------------------------------------------------------------
#define PST 72   // u16 row stride (64 data + 8 pad)

__global__ __launch_bounds__(512, 4) void flash_attn_mfma(
    unsigned short* QAhi, unsigned short* QAlo,   // Q in, attn out (aliased)
    const unsigned short* __restrict__ Khi, const unsigned short* __restrict__ Klo,
    const unsigned short* __restrict__ vThi, const unsigned short* __restrict__ vTlo)
{
    __shared__ unsigned short KhiS[64 * PST];
    __shared__ unsigned short KloS[64 * PST];
    __shared__ unsigned short VhiS[64 * PST];   // V^T tile [d][s]
    __shared__ unsigned short VloS[64 * PST];
    __shared__ unsigned short PhS[128 * PST];
    __shared__ unsigned short PlS[128 * PST];

    const int t    = threadIdx.x;
    const int pj   = blockIdx.x;            // 0..7
    const int bh   = blockIdx.y;
    const int b    = bh >> 4, h = bh & 15;
    const int lane = t & 63, w = t >> 6;    // 8 waves
    const int lm   = lane & 15, quad = lane >> 4;

    const int srow = t >> 3;                // 0..63
    const int sseg = (t & 7) * 8;           // u16 col 0..56

    const unsigned short* Kh_b = Khi + (size_t)(b * S_) * D_ + h * HD + sseg;
    const unsigned short* Kl_b = Klo + (size_t)(b * S_) * D_ + h * HD + sseg;
    const unsigned short* Vh_b = vThi + ((size_t)((b * 16 + h) * 64 + srow)) * S_ + sseg;
    const unsigned short* Vl_b = vTlo + ((size_t)((b * 16 + h) * 64 + srow)) * S_ + sseg;

    for (int phse = 0; phse < 2; phse++) {
        const int qt = phse ? (15 - pj) : pj;
        const int q0 = qt * 128;
        const int ntiles = 2 * qt + 2;
        const int wdiag = (q0 >> 6) + (w >> 2);   // wave's diagonal k-tile

        // Q fragments (A-layout rows q0+16w+lm), pre-scaled by 1/8
        short8 qh[2], ql[2];
        {
            const size_t qoff = (size_t)(b * S_ + q0 + 16 * w + lm) * D_ + h * HD + quad * 8;
            qh[0] = *(const short8*)&QAhi[qoff];
            qh[1] = *(const short8*)&QAhi[qoff + 32];
            ql[0] = *(const short8*)&QAlo[qoff];
            ql[1] = *(const short8*)&QAlo[qoff + 32];
        }

        float lsum[4] = {0.f, 0.f, 0.f, 0.f};
        floatx4 o[4];
#pragma unroll
        for (int nb = 0; nb < 4; nb++)
#pragma unroll
            for (int r = 0; r < 4; r++) o[nb][r] = 0.f;

        // prefetch tile 0 staging data (1 uint4 per thread per array)
        uint4 pkh, pkl, pvh, pvl;
        pkh = *(const uint4*)(Kh_b + (size_t)srow * D_);
        pkl = *(const uint4*)(Kl_b + (size_t)srow * D_);
        pvh = *(const uint4*)(Vh_b);
        pvl = *(const uint4*)(Vl_b);

        for (int kt = 0; kt < ntiles; kt++) {
            __syncthreads();   // all waves done reading previous K/V tile
            *(uint4*)&KhiS[srow * PST + sseg] = pkh;
            *(uint4*)&KloS[srow * PST + sseg] = pkl;
            *(uint4*)&VhiS[srow * PST + sseg] = pvh;
            *(uint4*)&VloS[srow * PST + sseg] = pvl;
            __syncthreads();   // tile staged

            if (kt + 1 < ntiles) {   // prefetch next tile (hidden by compute)
                const int k1 = (kt + 1) * 64;
                pkh = *(const uint4*)(Kh_b + (size_t)(k1 + srow) * D_);
                pkl = *(const uint4*)(Kl_b + (size_t)(k1 + srow) * D_);
                pvh = *(const uint4*)(Vh_b + k1);
                pvl = *(const uint4*)(Vl_b + k1);
            }

            if (kt <= wdiag) {   // wave-uniform causal skip
                // ---- S = Q K^T (3-MFMA split)
                floatx4 sa[4];
#pragma unroll
                for (int nb = 0; nb < 4; nb++)
#pragma unroll
                    for (int r = 0; r < 4; r++) sa[nb][r] = 0.f;
#pragma unroll
                for (int s = 0; s < 2; s++) {
#pragma unroll
                    for (int nb = 0; nb < 4; nb++) {
                        short8 kh = *(const short8*)&KhiS[(nb * 16 + lm) * PST + s * 32 + quad * 8];
                        short8 kl = *(const short8*)&KloS[(nb * 16 + lm) * PST + s * 32 + quad * 8];
                        sa[nb] = __builtin_amdgcn_mfma_f32_16x16x32_bf16(qh[s], kh, sa[nb], 0, 0, 0);
                        sa[nb] = __builtin_amdgcn_mfma_f32_16x16x32_bf16(ql[s], kh, sa[nb], 0, 0, 0);
                        sa[nb] = __builtin_amdgcn_mfma_f32_16x16x32_bf16(qh[s], kl, sa[nb], 0, 0, 0);
                    }
                }

                // ---- softmax-lite (no shift); mask only on the diag tile
                const bool diag = (kt == wdiag);
                const int kbase = kt * 64;
#pragma unroll
                for (int r = 0; r < 4; r++) {
                    const int qabs = q0 + 16 * w + 4 * quad + r;
                    const int rloc = 16 * w + 4 * quad + r;
#pragma unroll
                    for (int nb = 0; nb < 4; nb++) {
                        float p = __expf(sa[nb][r]);
                        if (diag && (kbase + 16 * nb + lm > qabs)) p = 0.f;
                        lsum[r] += p;
                        unsigned short hh, ll;
                        split2(p, hh, ll);
                        PhS[rloc * PST + 16 * nb + lm] = hh;
                        PlS[rloc * PST + 16 * nb + lm] = ll;
                    }
                }

                // ---- O += P V (same-wave P rows; lgkmcnt ordering)
#pragma unroll
                for (int ks = 0; ks < 2; ks++) {
                    short8 pf = *(const short8*)&PhS[(16 * w + lm) * PST + ks * 32 + quad * 8];
                    short8 pg = *(const short8*)&PlS[(16 * w + lm) * PST + ks * 32 + quad * 8];
#pragma unroll
                    for (int nb = 0; nb < 4; nb++) {
                        short8 vhf = *(const short8*)&VhiS[(16 * nb + lm) * PST + ks * 32 + quad * 8];
                        short8 vlf = *(const short8*)&VloS[(16 * nb + lm) * PST + ks * 32 + quad * 8];
                        o[nb] = __builtin_amdgcn_mfma_f32_16x16x32_bf16(pf, vhf, o[nb], 0, 0, 0);
                        o[nb] = __builtin_amdgcn_mfma_f32_16x16x32_bf16(pg, vhf, o[nb], 0, 0, 0);
                        o[nb] = __builtin_amdgcn_mfma_f32_16x16x32_bf16(pf, vlf, o[nb], 0, 0, 0);
                    }
                }
            }
        }

        // epilogue: reduce l, normalize, write attn PRE-SPLIT into Q buffers
#pragma unroll
        for (int r = 0; r < 4; r++) {
            float l = lsum[r];
            l += __shfl_xor(l, 1);
            l += __shfl_xor(l, 2);
            l += __shfl_xor(l, 4);
            l += __shfl_xor(l, 8);
            const float inv = 1.f / l;
            const size_t rowoff =
                (size_t)(b * S_ + q0 + 16 * w + 4 * quad + r) * D_ + h * HD + lm;
#pragma unroll
            for (int nb = 0; nb < 4; nb++) {
                unsigned short hh, ll;
                split2(o[nb][r] * inv, hh, ll);
                QAhi[rowoff + 16 * nb] = hh;
                QAlo[rowoff + 16 * nb] = ll;
            }
        }
    }
}

// ---------------------------------------------------------------------------
extern "C" void kernel_launch(void* const* d_in, const int* in_sizes, int n_in,
                              void* d_out, int out_size, void* d_ws, size_t ws_size,
                              hipStream_t stream)
{
    const float* hs     = (const float*)d_in[0];
    const float* attn_w = (const float*)d_in[1];
    const float* attn_b = (const float*)d_in[2];
    const float* proj_w = (const float*)d_in[3];
    const float* proj_b = (const float*)d_in[4];
    float* outp = (float*)d_out;

    const size_t QE = (size_t)M_ * D_;          // 4,194,304
    const size_t WQ = (size_t)D_ * N_QKV;       // 3,145,728
    unsigned short* Qhi   = (unsigned short*)d_ws;       // also attn hi
    unsigned short* Qlo   = Qhi + QE;                    // also attn lo
    unsigned short* Khi   = Qlo + QE;
    unsigned short* Klo   = Khi + QE;
    unsigned short* vThi  = Klo + QE;
    unsigned short* vTlo  = vThi + QE;
    unsigned short* WqThi = vTlo + QE;
    unsigned short* WqTlo = WqThi + WQ;
    unsigned short* WpThi = WqTlo + WQ;
    unsigned short* WpTlo = WpThi + (size_t)D_ * D_;     // total = 64 MB exactly

    dim3 blk(256);
    prep_wT<<<dim3(N_QKV / 64, D_ / 64), blk, 0, stream>>>(attn_w, N_QKV, WqThi, WqTlo);
    prep_wT<<<dim3(D_ / 64, D_ / 64), blk, 0, stream>>>(proj_w, D_, WpThi, WpTlo);
    gemm_qkv<<<dim3(N_QKV / 128, M_ / 128), blk, 0, stream>>>(
        hs, WqThi, WqTlo, attn_b, Qhi, Qlo, Khi, Klo, vThi, vTlo);
    flash_attn_mfma<<<dim3(8, B_ * H_), dim3(512), 0, stream>>>(
        Qhi, Qlo, Khi, Klo, vThi, vTlo);
    gemm_out<<<dim3(D_ / 64, M_ / 64), blk, 0, stream>>>(
        Qhi, Qlo, WpThi, WpTlo, proj_b, outp);
}